// Round 6
// baseline (323.658 us; speedup 1.0000x reference)
//
#include <hip/hip_runtime.h>
#include <cstdint>
#include <cstddef>

#define NN 16384
#define CC 64
#define LN_EPS 1e-5f

typedef __attribute__((ext_vector_type(8))) short short8;
typedef __attribute__((ext_vector_type(4))) float f32x4;
typedef unsigned short ushort_t;
typedef unsigned int uint32;

__device__ __forceinline__ ushort_t f2bf(float f) {
  union { float f; uint32 u; } v; v.f = f;
  return (ushort_t)((v.u + 0x8000u) >> 16);
}
__device__ __forceinline__ uint32 pk2(float a, float b) {
  union { float f; uint32 u; } x, y; x.f = a; y.f = b;
  return ((x.u + 0x8000u) >> 16) | ((y.u + 0x8000u) & 0xffff0000u);
}
__device__ __forceinline__ short8 pk8(float4 a, float4 b) {
  union { short8 s; uint32 u[4]; } r;
  r.u[0] = pk2(a.x, a.y); r.u[1] = pk2(a.z, a.w);
  r.u[2] = pk2(b.x, b.y); r.u[3] = pk2(b.z, b.w);
  return r.s;
}

// ---------------- prep: w3[kh][o][k'=kw*64+i] bf16 from sr_w (OIHW)
__global__ void prep_kernel(const float* __restrict__ sr_w, ushort_t* __restrict__ w3) {
  int e = blockIdx.x*256 + threadIdx.x;
  int kh = e >> 15, rem = e & 32767, o = rem >> 9, kp = rem & 511;
  int kw = kp >> 6, i = kp & 63;
  w3[e] = f2bf(sr_w[o*4096 + i*64 + kh*8 + kw]);
}

// ---------------- stage1: fused q-proj + conv k-chunk. Block = 128 rows of x = one image row
// = 16 patches x (one kh) x 512 k' contiguous. qproj -> q_ws; conv partial -> part[kh][p][o].
__global__ __launch_bounds__(256) void stage1_kernel(const float* __restrict__ x,
    const float* __restrict__ q_w, const float* __restrict__ q_b,
    const ushort_t* __restrict__ w3, ushort_t* __restrict__ q_out, float* __restrict__ part) {
  __shared__ __align__(16) ushort_t x_tile[16*520];   // [pw][k'], pitch 520
  __shared__ __align__(16) ushort_t q_tile[128*64];
  int t = threadIdx.x;
  int g = blockIdx.x;
  int b = g >> 7;              // 128 blocks per batch
  int r_img = g & 127;
  int kh = r_img & 7, ph = r_img >> 3;
  size_t gr0 = (size_t)g * 128;
  const float* xblk = &x[gr0*64];       // 8192 contiguous floats
  // conv A staging: 8192 floats -> bf16, patch-major (identity mapping: pw*512 + k')
  #pragma unroll
  for (int v = 0; v < 4; ++v) {
    int e8 = v*256 + t;
    int pw = e8 >> 6, kp8 = (e8 & 63)*8;
    const float* s = xblk + e8*8;
    *(short8*)&x_tile[pw*520 + kp8] = pk8(*(const float4*)s, *(const float4*)(s + 4));
  }
  int w = t >> 6, lane = t & 63, quad = lane >> 4, col = lane & 15;
  const float qscale = 0.17677669529663687f * 1.4426950408889634f; // D^-0.5 * log2(e)
  short8 bfr[4][2];
  float qb[4];
  #pragma unroll
  for (int ct = 0; ct < 4; ++ct) {
    #pragma unroll
    for (int ksb = 0; ksb < 2; ++ksb) {
      const float* src = &q_w[(ct*16 + col)*64 + ksb*32 + quad*8];
      bfr[ct][ksb] = pk8(*(const float4*)src, *(const float4*)(src + 4));
    }
    qb[ct] = q_b[ct*16 + col];
  }
  const f32x4 zero = {0.f, 0.f, 0.f, 0.f};
  // qproj: 2 m-tiles per wave (rows w*32 .. w*32+31), A-frags direct from global (L1-hot)
  #pragma unroll
  for (int mt = 0; mt < 2; ++mt) {
    int row = w*32 + mt*16 + col;
    const float* xs = xblk + row*64;
    short8 af0 = pk8(*(const float4*)&xs[quad*8],      *(const float4*)&xs[quad*8 + 4]);
    short8 af1 = pk8(*(const float4*)&xs[32 + quad*8], *(const float4*)&xs[36 + quad*8]);
    #pragma unroll
    for (int ct = 0; ct < 4; ++ct) {
      f32x4 acc = __builtin_amdgcn_mfma_f32_16x16x32_bf16(af0, bfr[ct][0], zero, 0, 0, 0);
      acc = __builtin_amdgcn_mfma_f32_16x16x32_bf16(af1, bfr[ct][1], acc, 0, 0, 0);
      #pragma unroll
      for (int r = 0; r < 4; ++r)
        q_tile[(w*32 + mt*16 + quad*4 + r)*64 + ct*16 + col] = f2bf((acc[r] + qb[ct]) * qscale);
    }
  }
  __syncthreads();
  // conv: M=16 patches, N=64 (wave w -> o = w*16..+15), K=512; B-frags from w3 via L2
  {
    const ushort_t* wbase = &w3[kh*32768 + (w*16 + col)*512 + quad*8];
    const ushort_t* abase = &x_tile[col*520 + quad*8];
    f32x4 acc = zero;
    #pragma unroll
    for (int ks = 0; ks < 16; ++ks) {
      short8 af = *(const short8*)(abase + ks*32);
      short8 bf = *(const short8*)(wbase + ks*32);
      acc = __builtin_amdgcn_mfma_f32_16x16x32_bf16(af, bf, acc, 0, 0, 0);
    }
    #pragma unroll
    for (int r = 0; r < 4; ++r) {
      int p = b*256 + ph*16 + quad*4 + r;
      part[kh*65536 + p*64 + w*16 + col] = acc[r];
    }
  }
  // q stores (packed uint4, head-split layout)
  #pragma unroll
  for (int s = 0; s < 4; ++s) {
    int u = s*256 + t;
    int row = u >> 3, seg = u & 7;
    int h2 = seg >> 2, sg = seg & 3;
    uint4 val = *(const uint4*)&q_tile[row*64 + seg*8];
    int n = r_img*128 + row;
    *(uint4*)&q_out[((size_t)(b*2 + h2)*NN + n)*32 + sg*8] = val;
  }
}

// ---------------- LN + kv proj (reduces 8 conv partials) -> k[bh][m][d], vT[bh][d][m] (bf16)
__global__ __launch_bounds__(256) void lnkv_kernel(const float* __restrict__ part,
    const float* __restrict__ sr_b, const float* __restrict__ ln_g, const float* __restrict__ ln_b,
    const float* __restrict__ kv_w, const float* __restrict__ kv_b,
    ushort_t* __restrict__ k_out, ushort_t* __restrict__ v_out) {
  __shared__ float xsrow[4][64];
  int t = threadIdx.x;
  int w = t >> 6, lane = t & 63;
  float4 wk[16], wv[16];
  #pragma unroll
  for (int c4 = 0; c4 < 16; ++c4) {
    wk[c4] = *(const float4*)&kv_w[lane*64 + c4*4];
    wv[c4] = *(const float4*)&kv_w[(64+lane)*64 + c4*4];
  }
  float kb0 = kv_b[lane], kb1 = kv_b[64+lane];
  float sb = sr_b[lane], lg = ln_g[lane], lb = ln_b[lane];
  int h = lane >> 5, dd = lane & 31;
  for (int i = 0; i < 2; ++i) {
    int row = blockIdx.x*8 + w*2 + i;
    float xc = sb;
    #pragma unroll
    for (int kc = 0; kc < 8; ++kc) xc += part[kc*65536 + row*64 + lane];
    float s = xc;
    #pragma unroll
    for (int m = 1; m < 64; m <<= 1) s += __shfl_xor(s, m);
    float mu = s * (1.0f/64.0f);
    float d0 = xc - mu;
    float vs = d0*d0;
    #pragma unroll
    for (int m = 1; m < 64; m <<= 1) vs += __shfl_xor(vs, m);
    float rs = rsqrtf(vs*(1.0f/64.0f) + LN_EPS);
    xsrow[w][lane] = d0*rs*lg + lb;   // wave-private row: lgkmcnt orders, no barrier
    float acc0 = kb0, acc1 = kb1;
    #pragma unroll
    for (int c4 = 0; c4 < 16; ++c4) {
      float4 xv = *(const float4*)&xsrow[w][c4*4];
      acc0 += xv.x*wk[c4].x + xv.y*wk[c4].y + xv.z*wk[c4].z + xv.w*wk[c4].w;
      acc1 += xv.x*wv[c4].x + xv.y*wv[c4].y + xv.z*wv[c4].z + xv.w*wv[c4].w;
    }
    int b = row >> 8, m2 = row & 255;
    int bh = b*2 + h;
    k_out[(bh*256 + m2)*32 + dd] = f2bf(acc0);
    v_out[(bh*32 + dd)*256 + m2] = f2bf(acc1);
  }
}

// ---------------- attn2: both heads + fused out-proj. S^T=K.Q^T -> softmax -> O^T=V^T.(P^T|pos^T)
// -> o_lds -> out^T = projW . O_full^T -> fp32 out. K/V frags from L2 (no LDS staging, no barriers).
__global__ __launch_bounds__(256, 2) void attn2_kernel(const ushort_t* __restrict__ q_ws,
    const ushort_t* __restrict__ k_ws, const ushort_t* __restrict__ v_ws,
    const float* __restrict__ pos, const float* __restrict__ alpha,
    const float* __restrict__ proj_w, const float* __restrict__ proj_b,
    float* __restrict__ out) {
  __shared__ __align__(16) ushort_t p_lds[4][16*264];  // wave-private P^T [qrow][key]
  __shared__ __align__(16) ushort_t o_lds[4][16*72];   // wave-private O [qrow][c], pitch 72
  int t = threadIdx.x;
  int b = blockIdx.x >> 6, blk = blockIdx.x & 63;
  int w = t >> 6, lane = t & 63, quad = lane >> 4, col = lane & 15;
  float a = alpha[0];
  float one_minus_a = 1.0f - a;
  // resident proj-W A-frags: A[m=o][k=c]
  short8 pwf[4][2];
  #pragma unroll
  for (int ct = 0; ct < 4; ++ct) {
    #pragma unroll
    for (int ks2 = 0; ks2 < 2; ++ks2) {
      const float* src = &proj_w[(ct*16 + col)*64 + ks2*32 + quad*8];
      pwf[ct][ks2] = pk8(*(const float4*)src, *(const float4*)(src + 4));
    }
  }
  const f32x4 zero = {0.f, 0.f, 0.f, 0.f};
  for (int it = 0; it < 4; ++it) {
    int n0 = blk*256 + (it*4 + w)*16;
    #pragma unroll
    for (int h = 0; h < 2; ++h) {
      int bh = b*2 + h;
      // pos loads (B-frag order) — HBM stream, latency hidden under QK+softmax
      float4 p4[16];
      const float* pbase = &pos[((size_t)bh*NN + n0 + col)*256 + quad*8];
      #pragma unroll
      for (int ks = 0; ks < 8; ++ks) {
        p4[ks*2]   = *(const float4*)(pbase + ks*32);
        p4[ks*2+1] = *(const float4*)(pbase + ks*32 + 4);
      }
      short8 qa = *(const short8*)&q_ws[((size_t)bh*NN + n0 + col)*32 + quad*8];
      f32x4 st[16];
      #pragma unroll
      for (int tt = 0; tt < 16; ++tt) {   // K A-frags straight from L2
        short8 kb = *(const short8*)&k_ws[((size_t)bh*256 + tt*16 + col)*32 + quad*8];
        st[tt] = __builtin_amdgcn_mfma_f32_16x16x32_bf16(kb, qa, zero, 0, 0, 0);  // S^T
      }
      float sum = 0.f;
      #pragma unroll
      for (int tt = 0; tt < 16; ++tt) {
        #pragma unroll
        for (int r = 0; r < 4; ++r) {
          float e = __builtin_amdgcn_exp2f(st[tt][r]);   // |logit*log2e| < 1: no max needed
          st[tt][r] = e; sum += e;
        }
      }
      sum += __shfl_xor(sum, 16);
      sum += __shfl_xor(sum, 32);
      float coef = one_minus_a * __builtin_amdgcn_rcpf(sum);
      #pragma unroll
      for (int tt = 0; tt < 16; ++tt) {
        uint2 val = { pk2(st[tt][0], st[tt][1]), pk2(st[tt][2], st[tt][3]) };
        *(uint2*)&p_lds[w][col*264 + tt*16 + quad*4] = val;
      }
      f32x4 o0 = zero, o1 = zero, e0 = zero, e1 = zero;
      #pragma unroll
      for (int ks = 0; ks < 8; ++ks) {     // V A-frags from L2, P^T from wave-private LDS
        short8 pa  = *(const short8*)&p_lds[w][col*264 + ks*32 + quad*8];
        short8 vb0 = *(const short8*)&v_ws[((size_t)bh*32 + col)*256 + ks*32 + quad*8];
        short8 vb1 = *(const short8*)&v_ws[((size_t)bh*32 + 16 + col)*256 + ks*32 + quad*8];
        short8 pf  = pk8(p4[ks*2], p4[ks*2+1]);
        o0 = __builtin_amdgcn_mfma_f32_16x16x32_bf16(vb0, pa, o0, 0, 0, 0);
        o1 = __builtin_amdgcn_mfma_f32_16x16x32_bf16(vb1, pa, o1, 0, 0, 0);
        e0 = __builtin_amdgcn_mfma_f32_16x16x32_bf16(vb0, pf, e0, 0, 0, 0);
        e1 = __builtin_amdgcn_mfma_f32_16x16x32_bf16(vb1, pf, e1, 0, 0, 0);
      }
      // O rows (bf16) -> o_lds[qrow][c], c = h*32 + half*16 + quad*4..+3
      uint2 u0 = { pk2(coef*o0[0] + a*e0[0], coef*o0[1] + a*e0[1]),
                   pk2(coef*o0[2] + a*e0[2], coef*o0[3] + a*e0[3]) };
      uint2 u1 = { pk2(coef*o1[0] + a*e1[0], coef*o1[1] + a*e1[1]),
                   pk2(coef*o1[2] + a*e1[2], coef*o1[3] + a*e1[3]) };
      *(uint2*)&o_lds[w][col*72 + h*32 + quad*4]      = u0;
      *(uint2*)&o_lds[w][col*72 + h*32 + 16 + quad*4] = u1;
    }
    // fused out-proj: D[m=o][n=qrow] = projW . O^T ; B-frags from o_lds (wave-private)
    short8 ob0 = *(const short8*)&o_lds[w][col*72 + quad*8];
    short8 ob1 = *(const short8*)&o_lds[w][col*72 + 32 + quad*8];
    #pragma unroll
    for (int ct = 0; ct < 4; ++ct) {
      f32x4 acc = __builtin_amdgcn_mfma_f32_16x16x32_bf16(pwf[ct][0], ob0, zero, 0, 0, 0);
      acc = __builtin_amdgcn_mfma_f32_16x16x32_bf16(pwf[ct][1], ob1, acc, 0, 0, 0);
      float4 pbv = *(const float4*)&proj_b[ct*16 + quad*4];
      float4 res = { acc[0] + pbv.x, acc[1] + pbv.y, acc[2] + pbv.z, acc[3] + pbv.w };
      *(float4*)&out[((size_t)b*NN + n0 + col)*64 + ct*16 + quad*4] = res;
    }
  }
}

extern "C" void kernel_launch(void* const* d_in, const int* in_sizes, int n_in,
                              void* d_out, int out_size, void* d_ws, size_t ws_size,
                              hipStream_t stream) {
  const float* x      = (const float*)d_in[0];
  const float* pos    = (const float*)d_in[1];
  const float* q_w    = (const float*)d_in[2];
  const float* q_b    = (const float*)d_in[3];
  const float* kv_w   = (const float*)d_in[4];
  const float* kv_b   = (const float*)d_in[5];
  const float* proj_w = (const float*)d_in[6];
  const float* proj_b = (const float*)d_in[7];
  const float* sr_w   = (const float*)d_in[8];
  const float* sr_b   = (const float*)d_in[9];
  const float* ln_g   = (const float*)d_in[10];
  const float* ln_b   = (const float*)d_in[11];
  const float* alpha  = (const float*)d_in[12];
  float* out = (float*)d_out;

  char* ws = (char*)d_ws;
  float* part       = (float*)(ws);                      // 2 MB: conv partials [8][1024][64]
  ushort_t* w3      = (ushort_t*)(ws + (2u<<20));        // 512 KB: bf16 W [kh][o][k']
  ushort_t* k_ws    = (ushort_t*)(ws + (3u<<20));        // 128 KB
  ushort_t* v_ws    = (ushort_t*)(ws + (3u<<20) + (128u<<10)); // 128 KB
  ushort_t* q_ws    = (ushort_t*)(ws + (4u<<20));        // 8 MB

  hipLaunchKernelGGL(prep_kernel,   dim3(1024), dim3(256), 0, stream, sr_w, w3);
  hipLaunchKernelGGL(stage1_kernel, dim3(512),  dim3(256), 0, stream, x, q_w, q_b, w3, q_ws, part);
  hipLaunchKernelGGL(lnkv_kernel,   dim3(128),  dim3(256), 0, stream, part, sr_b, ln_g, ln_b, kv_w, kv_b, k_ws, v_ws);
  hipLaunchKernelGGL(attn2_kernel,  dim3(256),  dim3(256), 0, stream, q_ws, k_ws, v_ws, pos, alpha, proj_w, proj_b, out);
}

// Round 7
// 259.233 us; speedup vs baseline: 1.2485x; 1.2485x over previous
//
#include <hip/hip_runtime.h>
#include <cstdint>
#include <cstddef>

#define NN 16384
#define CC 64
#define LN_EPS 1e-5f

typedef __attribute__((ext_vector_type(8))) short short8;
typedef __attribute__((ext_vector_type(4))) float f32x4;
typedef unsigned short ushort_t;
typedef unsigned int uint32;

__device__ __forceinline__ ushort_t f2bf(float f) {
  union { float f; uint32 u; } v; v.f = f;
  return (ushort_t)((v.u + 0x8000u) >> 16);
}
__device__ __forceinline__ uint32 pk2(float a, float b) {
  union { float f; uint32 u; } x, y; x.f = a; y.f = b;
  return ((x.u + 0x8000u) >> 16) | ((y.u + 0x8000u) & 0xffff0000u);
}
__device__ __forceinline__ short8 pk8(float4 a, float4 b) {
  union { short8 s; uint32 u[4]; } r;
  r.u[0] = pk2(a.x, a.y); r.u[1] = pk2(a.z, a.w);
  r.u[2] = pk2(b.x, b.y); r.u[3] = pk2(b.z, b.w);
  return r.s;
}

// ---------------- prep: w3[kh][o][k'=kw*64+i] bf16 from sr_w (OIHW)
__global__ void prep_kernel(const float* __restrict__ sr_w, ushort_t* __restrict__ w3) {
  int e = blockIdx.x*256 + threadIdx.x;
  int kh = e >> 15, rem = e & 32767, o = rem >> 9, kp = rem & 511;
  int kw = kp >> 6, i = kp & 63;
  w3[e] = f2bf(sr_w[o*4096 + i*64 + kh*8 + kw]);
}

// ---------------- stage1: fused q-proj + conv k-chunk. Block = 128 rows of x = one image row
__global__ __launch_bounds__(256) void stage1_kernel(const float* __restrict__ x,
    const float* __restrict__ q_w, const float* __restrict__ q_b,
    const ushort_t* __restrict__ w3, ushort_t* __restrict__ q_out, float* __restrict__ part) {
  __shared__ __align__(16) ushort_t x_tile[16*520];   // [pw][k'], pitch 520
  __shared__ __align__(16) ushort_t q_tile[128*64];
  int t = threadIdx.x;
  int g = blockIdx.x;
  int b = g >> 7;
  int r_img = g & 127;
  int kh = r_img & 7, ph = r_img >> 3;
  size_t gr0 = (size_t)g * 128;
  const float* xblk = &x[gr0*64];
  #pragma unroll
  for (int v = 0; v < 4; ++v) {
    int e8 = v*256 + t;
    int pw = e8 >> 6, kp8 = (e8 & 63)*8;
    const float* s = xblk + e8*8;
    *(short8*)&x_tile[pw*520 + kp8] = pk8(*(const float4*)s, *(const float4*)(s + 4));
  }
  int w = t >> 6, lane = t & 63, quad = lane >> 4, col = lane & 15;
  const float qscale = 0.17677669529663687f * 1.4426950408889634f; // D^-0.5 * log2(e)
  short8 bfr[4][2];
  float qb[4];
  #pragma unroll
  for (int ct = 0; ct < 4; ++ct) {
    #pragma unroll
    for (int ksb = 0; ksb < 2; ++ksb) {
      const float* src = &q_w[(ct*16 + col)*64 + ksb*32 + quad*8];
      bfr[ct][ksb] = pk8(*(const float4*)src, *(const float4*)(src + 4));
    }
    qb[ct] = q_b[ct*16 + col];
  }
  const f32x4 zero = {0.f, 0.f, 0.f, 0.f};
  #pragma unroll
  for (int mt = 0; mt < 2; ++mt) {
    int row = w*32 + mt*16 + col;
    const float* xs = xblk + row*64;
    short8 af0 = pk8(*(const float4*)&xs[quad*8],      *(const float4*)&xs[quad*8 + 4]);
    short8 af1 = pk8(*(const float4*)&xs[32 + quad*8], *(const float4*)&xs[36 + quad*8]);
    #pragma unroll
    for (int ct = 0; ct < 4; ++ct) {
      f32x4 acc = __builtin_amdgcn_mfma_f32_16x16x32_bf16(af0, bfr[ct][0], zero, 0, 0, 0);
      acc = __builtin_amdgcn_mfma_f32_16x16x32_bf16(af1, bfr[ct][1], acc, 0, 0, 0);
      #pragma unroll
      for (int r = 0; r < 4; ++r)
        q_tile[(w*32 + mt*16 + quad*4 + r)*64 + ct*16 + col] = f2bf((acc[r] + qb[ct]) * qscale);
    }
  }
  __syncthreads();
  {
    const ushort_t* wbase = &w3[kh*32768 + (w*16 + col)*512 + quad*8];
    const ushort_t* abase = &x_tile[col*520 + quad*8];
    f32x4 acc = zero;
    #pragma unroll
    for (int ks = 0; ks < 16; ++ks) {
      short8 af = *(const short8*)(abase + ks*32);
      short8 bf = *(const short8*)(wbase + ks*32);
      acc = __builtin_amdgcn_mfma_f32_16x16x32_bf16(af, bf, acc, 0, 0, 0);
    }
    #pragma unroll
    for (int r = 0; r < 4; ++r) {
      int p = b*256 + ph*16 + quad*4 + r;
      part[kh*65536 + p*64 + w*16 + col] = acc[r];
    }
  }
  #pragma unroll
  for (int s = 0; s < 4; ++s) {
    int u = s*256 + t;
    int row = u >> 3, seg = u & 7;
    int h2 = seg >> 2, sg = seg & 3;
    uint4 val = *(const uint4*)&q_tile[row*64 + seg*8];
    int n = r_img*128 + row;
    *(uint4*)&q_out[((size_t)(b*2 + h2)*NN + n)*32 + sg*8] = val;
  }
}

// ---------------- LN + kv proj (reduces 8 conv partials) -> k[bh][m][d], vT[bh][d][m] (bf16)
__global__ __launch_bounds__(256) void lnkv_kernel(const float* __restrict__ part,
    const float* __restrict__ sr_b, const float* __restrict__ ln_g, const float* __restrict__ ln_b,
    const float* __restrict__ kv_w, const float* __restrict__ kv_b,
    ushort_t* __restrict__ k_out, ushort_t* __restrict__ v_out) {
  __shared__ float xsrow[4][64];
  int t = threadIdx.x;
  int w = t >> 6, lane = t & 63;
  float4 wk[16], wv[16];
  #pragma unroll
  for (int c4 = 0; c4 < 16; ++c4) {
    wk[c4] = *(const float4*)&kv_w[lane*64 + c4*4];
    wv[c4] = *(const float4*)&kv_w[(64+lane)*64 + c4*4];
  }
  float kb0 = kv_b[lane], kb1 = kv_b[64+lane];
  float sb = sr_b[lane], lg = ln_g[lane], lb = ln_b[lane];
  int h = lane >> 5, dd = lane & 31;
  for (int i = 0; i < 2; ++i) {
    int row = blockIdx.x*8 + w*2 + i;
    float xc = sb;
    #pragma unroll
    for (int kc = 0; kc < 8; ++kc) xc += part[kc*65536 + row*64 + lane];
    float s = xc;
    #pragma unroll
    for (int m = 1; m < 64; m <<= 1) s += __shfl_xor(s, m);
    float mu = s * (1.0f/64.0f);
    float d0 = xc - mu;
    float vs = d0*d0;
    #pragma unroll
    for (int m = 1; m < 64; m <<= 1) vs += __shfl_xor(vs, m);
    float rs = rsqrtf(vs*(1.0f/64.0f) + LN_EPS);
    xsrow[w][lane] = d0*rs*lg + lb;
    float acc0 = kb0, acc1 = kb1;
    #pragma unroll
    for (int c4 = 0; c4 < 16; ++c4) {
      float4 xv = *(const float4*)&xsrow[w][c4*4];
      acc0 += xv.x*wk[c4].x + xv.y*wk[c4].y + xv.z*wk[c4].z + xv.w*wk[c4].w;
      acc1 += xv.x*wv[c4].x + xv.y*wv[c4].y + xv.z*wv[c4].z + xv.w*wv[c4].w;
    }
    int b = row >> 8, m2 = row & 255;
    int bh = b*2 + h;
    k_out[(bh*256 + m2)*32 + dd] = f2bf(acc0);
    v_out[(bh*32 + dd)*256 + m2] = f2bf(acc1);
  }
}

// ---------------- attn3: both heads + fused out-proj, 64-query blocks for occupancy.
// S^T=K.Q^T -> softmax -> O^T=V^T.(P^T|pos^T) -> o_lds -> out = projW.O^T. K/V from L2.
__global__ __launch_bounds__(256, 3) void attn3_kernel(const ushort_t* __restrict__ q_ws,
    const ushort_t* __restrict__ k_ws, const ushort_t* __restrict__ v_ws,
    const float* __restrict__ pos, const float* __restrict__ alpha,
    const float* __restrict__ proj_w, const float* __restrict__ proj_b,
    float* __restrict__ out) {
  __shared__ __align__(16) ushort_t p_lds[4][16*264];  // wave-private P^T [qrow][key]
  __shared__ __align__(16) ushort_t o_lds[4][16*72];   // wave-private O [qrow][c], pitch 72
  int t = threadIdx.x;
  int b = blockIdx.x >> 8, tile = blockIdx.x & 255;
  int w = t >> 6, lane = t & 63, quad = lane >> 4, col = lane & 15;
  int n0 = tile*64 + w*16;
  float a = alpha[0];
  float one_minus_a = 1.0f - a;
  // resident proj-W A-frags: A[m=o][k=c]
  short8 pwf[4][2];
  #pragma unroll
  for (int ct = 0; ct < 4; ++ct) {
    #pragma unroll
    for (int ks2 = 0; ks2 < 2; ++ks2) {
      const float* src = &proj_w[(ct*16 + col)*64 + ks2*32 + quad*8];
      pwf[ct][ks2] = pk8(*(const float4*)src, *(const float4*)(src + 4));
    }
  }
  const f32x4 zero = {0.f, 0.f, 0.f, 0.f};
  #pragma unroll
  for (int h = 0; h < 2; ++h) {
    int bh = b*2 + h;
    const float* pbase = &pos[((size_t)bh*NN + n0 + col)*256 + quad*8];
    // first half of pos loads issued before QK (latency under QK+softmax)
    float4 p4[16];
    #pragma unroll
    for (int ks = 0; ks < 4; ++ks) {
      p4[ks*2]   = *(const float4*)(pbase + ks*32);
      p4[ks*2+1] = *(const float4*)(pbase + ks*32 + 4);
    }
    short8 qa = *(const short8*)&q_ws[((size_t)bh*NN + n0 + col)*32 + quad*8];
    f32x4 st[16];
    #pragma unroll
    for (int tt = 0; tt < 16; ++tt) {   // K A-frags straight from L2
      short8 kb = *(const short8*)&k_ws[((size_t)bh*256 + tt*16 + col)*32 + quad*8];
      st[tt] = __builtin_amdgcn_mfma_f32_16x16x32_bf16(kb, qa, zero, 0, 0, 0);  // S^T
    }
    // second half of pos loads (latency under softmax + p_lds + early PV)
    #pragma unroll
    for (int ks = 4; ks < 8; ++ks) {
      p4[ks*2]   = *(const float4*)(pbase + ks*32);
      p4[ks*2+1] = *(const float4*)(pbase + ks*32 + 4);
    }
    float sum = 0.f;
    #pragma unroll
    for (int tt = 0; tt < 16; ++tt) {
      #pragma unroll
      for (int r = 0; r < 4; ++r) {
        float e = __builtin_amdgcn_exp2f(st[tt][r]);   // |logit*log2e| < 1: no max needed
        st[tt][r] = e; sum += e;
      }
    }
    sum += __shfl_xor(sum, 16);
    sum += __shfl_xor(sum, 32);
    float coef = one_minus_a * __builtin_amdgcn_rcpf(sum);
    #pragma unroll
    for (int tt = 0; tt < 16; ++tt) {
      uint2 val = { pk2(st[tt][0], st[tt][1]), pk2(st[tt][2], st[tt][3]) };
      *(uint2*)&p_lds[w][col*264 + tt*16 + quad*4] = val;
    }
    f32x4 o0 = zero, o1 = zero, e0 = zero, e1 = zero;
    #pragma unroll
    for (int ks = 0; ks < 8; ++ks) {     // V A-frags from L2, P^T wave-private LDS
      short8 pa  = *(const short8*)&p_lds[w][col*264 + ks*32 + quad*8];
      short8 vb0 = *(const short8*)&v_ws[((size_t)bh*32 + col)*256 + ks*32 + quad*8];
      short8 vb1 = *(const short8*)&v_ws[((size_t)bh*32 + 16 + col)*256 + ks*32 + quad*8];
      short8 pf  = pk8(p4[ks*2], p4[ks*2+1]);
      o0 = __builtin_amdgcn_mfma_f32_16x16x32_bf16(vb0, pa, o0, 0, 0, 0);
      o1 = __builtin_amdgcn_mfma_f32_16x16x32_bf16(vb1, pa, o1, 0, 0, 0);
      e0 = __builtin_amdgcn_mfma_f32_16x16x32_bf16(vb0, pf, e0, 0, 0, 0);
      e1 = __builtin_amdgcn_mfma_f32_16x16x32_bf16(vb1, pf, e1, 0, 0, 0);
    }
    uint2 u0 = { pk2(coef*o0[0] + a*e0[0], coef*o0[1] + a*e0[1]),
                 pk2(coef*o0[2] + a*e0[2], coef*o0[3] + a*e0[3]) };
    uint2 u1 = { pk2(coef*o1[0] + a*e1[0], coef*o1[1] + a*e1[1]),
                 pk2(coef*o1[2] + a*e1[2], coef*o1[3] + a*e1[3]) };
    *(uint2*)&o_lds[w][col*72 + h*32 + quad*4]      = u0;
    *(uint2*)&o_lds[w][col*72 + h*32 + 16 + quad*4] = u1;
  }
  // fused out-proj: D[m=o][n=qrow] = projW . O^T ; B-frags from wave-private o_lds
  short8 ob0 = *(const short8*)&o_lds[w][col*72 + quad*8];
  short8 ob1 = *(const short8*)&o_lds[w][col*72 + 32 + quad*8];
  #pragma unroll
  for (int ct = 0; ct < 4; ++ct) {
    f32x4 acc = __builtin_amdgcn_mfma_f32_16x16x32_bf16(pwf[ct][0], ob0, zero, 0, 0, 0);
    acc = __builtin_amdgcn_mfma_f32_16x16x32_bf16(pwf[ct][1], ob1, acc, 0, 0, 0);
    float4 pbv = *(const float4*)&proj_b[ct*16 + quad*4];
    float4 res = { acc[0] + pbv.x, acc[1] + pbv.y, acc[2] + pbv.z, acc[3] + pbv.w };
    *(float4*)&out[((size_t)b*NN + n0 + col)*64 + ct*16 + quad*4] = res;
  }
}

extern "C" void kernel_launch(void* const* d_in, const int* in_sizes, int n_in,
                              void* d_out, int out_size, void* d_ws, size_t ws_size,
                              hipStream_t stream) {
  const float* x      = (const float*)d_in[0];
  const float* pos    = (const float*)d_in[1];
  const float* q_w    = (const float*)d_in[2];
  const float* q_b    = (const float*)d_in[3];
  const float* kv_w   = (const float*)d_in[4];
  const float* kv_b   = (const float*)d_in[5];
  const float* proj_w = (const float*)d_in[6];
  const float* proj_b = (const float*)d_in[7];
  const float* sr_w   = (const float*)d_in[8];
  const float* sr_b   = (const float*)d_in[9];
  const float* ln_g   = (const float*)d_in[10];
  const float* ln_b   = (const float*)d_in[11];
  const float* alpha  = (const float*)d_in[12];
  float* out = (float*)d_out;

  char* ws = (char*)d_ws;
  float* part       = (float*)(ws);                      // 2 MB
  ushort_t* w3      = (ushort_t*)(ws + (2u<<20));        // 512 KB
  ushort_t* k_ws    = (ushort_t*)(ws + (3u<<20));        // 128 KB
  ushort_t* v_ws    = (ushort_t*)(ws + (3u<<20) + (128u<<10)); // 128 KB
  ushort_t* q_ws    = (ushort_t*)(ws + (4u<<20));        // 8 MB

  hipLaunchKernelGGL(prep_kernel,   dim3(1024), dim3(256), 0, stream, sr_w, w3);
  hipLaunchKernelGGL(stage1_kernel, dim3(512),  dim3(256), 0, stream, x, q_w, q_b, w3, q_ws, part);
  hipLaunchKernelGGL(lnkv_kernel,   dim3(128),  dim3(256), 0, stream, part, sr_b, ln_g, ln_b, kv_w, kv_b, k_ws, v_ws);
  hipLaunchKernelGGL(attn3_kernel,  dim3(1024), dim3(256), 0, stream, q_ws, k_ws, v_ws, pos, alpha, proj_w, proj_b, out);
}